// Round 11
// baseline (1136.449 us; speedup 1.0000x reference)
//
#include <hip/hip_runtime.h>
#include <hip/hip_bf16.h>

#define NNODES 20000
#define NEDGES 200000
#define NCD 32
#define FDIMD 13
#define FHIDD 64
#define NREPD 10
#define OUTCD (NCD * (NREPD + 1))   // 352
#define NCT 130                     // (64*32 + 32 bias) / 16 col tiles
#define NPB 4                       // nodes per k_msg block (19KB LDS -> 8 blocks/CU)
#define NBLK (NNODES / NPB)         // 5000
#define MAXTILES 40000
#define YKST 72                     // sY k-stride in u16 (64 + 8 pad, 144B)
#define YNST (32 * YKST)            // sY node stride in u16 (2304)

typedef short bf16x8 __attribute__((ext_vector_type(8)));
typedef float f32x4 __attribute__((ext_vector_type(4)));

// ---------------------------------------------------------------------------
__global__ __launch_bounds__(256) void k_copy_h0(const float* __restrict__ hx,
                                                 float* __restrict__ out,
                                                 __hip_bfloat16* __restrict__ hxb) {
    int tid = blockIdx.x * 256 + threadIdx.x;
    if (tid < NNODES * NCD) {
        float v = hx[tid];
        out[(size_t)(tid >> 5) * OUTCD + (tid & 31)] = v;
        hxb[tid] = __float2bfloat16(v);
    }
}

// in-degree (float + int) and out-degree (int)
__global__ __launch_bounds__(256) void k_degrees(const int* __restrict__ ei,
                                                 float* __restrict__ indeg,
                                                 int* __restrict__ incnt,
                                                 int* __restrict__ outcnt) {
    int e = blockIdx.x * 256 + threadIdx.x;
    if (e < NEDGES) {
        int d = ei[NEDGES + e];
        atomicAdd(&indeg[d], 1.0f);
        atomicAdd(&incnt[d], 1);
        atomicAdd(&outcnt[ei[e]], 1);
    }
}

// exclusive scan (generic length), single block
__global__ __launch_bounds__(256) void k_scan(const int* __restrict__ in,
                                              int* __restrict__ out, int n) {
    __shared__ int s_w[4];
    __shared__ int s_base;
    int t = threadIdx.x;
    if (t == 0) s_base = 0;
    __syncthreads();
    for (int base = 0; base < n; base += 256) {
        int i = base + t;
        int v = (i < n) ? in[i] : 0;
        int x = v;
        #pragma unroll
        for (int d = 1; d < 64; d <<= 1) {
            int y = __shfl_up(x, d);
            if ((t & 63) >= d) x += y;
        }
        if ((t & 63) == 63) s_w[t >> 6] = x;
        __syncthreads();
        int wid = t >> 6, wb = 0;
        for (int w = 0; w < wid; ++w) wb += s_w[w];
        if (i < n) out[i] = s_base + wb + x - v;
        int ctot = s_w[0] + s_w[1] + s_w[2] + s_w[3];
        __syncthreads();
        if (t == 0) s_base += ctot;
        __syncthreads();
    }
    if (t == 0) out[n] = s_base;
}

// rank[e] = src-sorted (CSR) position of edge e
__global__ __launch_bounds__(256) void k_fill(const int* __restrict__ ei,
                                              const int* __restrict__ csr_off,
                                              int* __restrict__ cursor,
                                              int* __restrict__ rank) {
    int e = blockIdx.x * 256 + threadIdx.x;
    if (e < NEDGES) {
        int s = ei[e];
        int p = atomicAdd(&cursor[s], 1);
        rank[e] = csr_off[s] + p;
    }
}

// cscpos[csr_pos] = dst-sorted (CSC) position of that edge
__global__ __launch_bounds__(256) void k_cpos(const int* __restrict__ ei,
                                              const int* __restrict__ rank,
                                              const int* __restrict__ csc_off,
                                              int* __restrict__ csc_cur,
                                              int* __restrict__ cscpos) {
    int e = blockIdx.x * 256 + threadIdx.x;
    if (e < NEDGES) {
        int dst = ei[NEDGES + e];
        int p = atomicAdd(&csc_cur[dst], 1);
        cscpos[rank[e]] = csc_off[dst] + p;
    }
}

// per-block (NPB-node) tile counts: sum ceil(deg/16)
__global__ __launch_bounds__(256) void k_tcnt(const int* __restrict__ csr_off,
                                              int* __restrict__ tcnt) {
    int b = blockIdx.x * 256 + threadIdx.x;
    if (b < NBLK) {
        int s = 0;
        for (int j = 0; j < NPB; ++j) {
            int d = csr_off[b * NPB + j + 1] - csr_off[b * NPB + j];
            s += (d + 15) >> 4;
        }
        tcnt[b] = s;
    }
}

// tiles[]: packed (start<<8 | cnt<<3 | local_row)
__global__ __launch_bounds__(256) void k_tfill(const int* __restrict__ csr_off,
                                               const int* __restrict__ tile_off,
                                               unsigned* __restrict__ tiles) {
    int b = blockIdx.x * 256 + threadIdx.x;
    if (b < NBLK) {
        int off = tile_off[b];
        for (int j = 0; j < NPB; ++j) {
            int s0 = csr_off[b * NPB + j];
            int d  = csr_off[b * NPB + j + 1] - s0;
            for (int q = 0; q < d; q += 16) {
                int cnt = d - q; if (cnt > 16) cnt = 16;
                tiles[off++] = ((unsigned)(s0 + q) << 8) | ((unsigned)cnt << 3) | (unsigned)j;
            }
        }
    }
}

// ---------------------------------------------------------------------------
// h1s[rank[e], k] = relu(ef[e] @ fW1 + fb1)[k], bf16, CSR-position order.
__global__ __launch_bounds__(256) void k_h1(const float* __restrict__ ef,
                                            const float* __restrict__ fW1,
                                            const float* __restrict__ fb1,
                                            const int* __restrict__ rank,
                                            __hip_bfloat16* __restrict__ h1s) {
    __shared__ float s_w1[FDIMD * FHIDD];
    __shared__ float s_ef[4 * FDIMD];
    __shared__ int s_rk[4];
    int t = threadIdx.x;
    for (int idx = t; idx < FDIMD * FHIDD; idx += 256) s_w1[idx] = fW1[idx];
    if (t < 4 * FDIMD) s_ef[t] = ef[(size_t)blockIdx.x * 4 * FDIMD + t];
    if (t < 4) s_rk[t] = rank[blockIdx.x * 4 + t];
    __syncthreads();
    int je = t >> 6, k = t & 63;
    float v = fb1[k];
    #pragma unroll
    for (int j = 0; j < FDIMD; ++j) v += s_ef[je * FDIMD + j] * s_w1[j * FHIDD + k];
    h1s[(size_t)s_rk[je] * FHIDD + k] = __float2bfloat16(fmaxf(v, 0.f));
}

// ---------------------------------------------------------------------------
// Lane-swizzled B-fragments of W2r (rearranged fW2 + fb2 bias cols).
__global__ __launch_bounds__(256) void k_w2frag(const float* __restrict__ fW2,
                                                const float* __restrict__ fb2,
                                                __hip_bfloat16* __restrict__ W2f) {
    int idx = blockIdx.x * 256 + threadIdx.x;
    if (idx >= NCT * 64) return;
    int ct = idx >> 6, lane = idx & 63;
    int j = ct * 16 + (lane & 15);
    __align__(16) __hip_bfloat16 tmp[8];
    #pragma unroll
    for (int jj = 0; jj < 8; ++jj) {
        int i = (lane >> 4) * 8 + jj;
        float v = (j < 2048) ? fW2[(size_t)(j >> 5) * 1024 + i * 32 + (j & 31)]
                             : fb2[i * 32 + (j - 2048)];
        tmp[jj] = __float2bfloat16(v);
    }
    *reinterpret_cast<uint4*>(&W2f[(size_t)ct * 1024 + lane * 8]) =
        *reinterpret_cast<const uint4*>(tmp);
}

// GRU weights transposed once: WiT[g*32+i] = Wi[i*96+g]
__global__ __launch_bounds__(256) void k_prep(const float* __restrict__ Wi,
                                              const float* __restrict__ Wh,
                                              float* __restrict__ WiT,
                                              float* __restrict__ WhT) {
    int idx = blockIdx.x * 256 + threadIdx.x;
    if (idx < 3072) {
        int g = idx >> 5, i = idx & 31;
        WiT[idx] = Wi[i * 96 + g];
        WhT[idx] = Wh[i * 96 + g];
    }
}

// ---------------------------------------------------------------------------
// Fused per 4-node block:
//  phase 1: Y = hxb @ W2r via MFMA -> LDS [node][o][k]; bias f32.
//  phase 2: per-wave loop over <=16-edge src tiles:
//           msg[16e x 32o] = H1[16x64] @ Y_src via 4 MFMAs; bias in acc init;
//           bf16 STORES to msgC at CSC positions (NO atomics).
__global__ __launch_bounds__(256) void k_msg(
    const int* __restrict__ tile_off, const unsigned* __restrict__ tiles,
    const int* __restrict__ cscpos, const __hip_bfloat16* __restrict__ h1s,
    const __hip_bfloat16* __restrict__ hxb, const __hip_bfloat16* __restrict__ W2f,
    __hip_bfloat16* __restrict__ msgC) {
    __shared__ __align__(16) unsigned short sY[NPB * YNST];  // 18,432 B
    __shared__ float s_bias[NPB][32];                        // 512 B
    const int t = threadIdx.x, lane = t & 63, wave = t >> 6;
    const int bid = blockIdx.x;
    const int t0 = tile_off[bid], t1 = tile_off[bid + 1];
    if (t0 == t1) return;
    const int n0 = bid * NPB;

    // ---- phase 1
    const int arow = (lane & 15) < NPB ? (lane & 15) : (NPB - 1);
    bf16x8 a = *reinterpret_cast<const bf16x8*>(
        hxb + (size_t)(n0 + arow) * NCD + (lane >> 4) * 8);
    const int colw = lane & 15, rbase = (lane >> 4) * 4;
    for (int ct = wave; ct < NCT; ct += 4) {
        bf16x8 b = *reinterpret_cast<const bf16x8*>(W2f + (size_t)ct * 1024 + lane * 8);
        f32x4 c = {0.f, 0.f, 0.f, 0.f};
        c = __builtin_amdgcn_mfma_f32_16x16x32_bf16(a, b, c, 0, 0, 0);
        if (rbase < NPB) {        // lanes 0..15 hold rows 0..3
            const int j = ct * 16 + colw;
            if (j < 2048) {
                const int k = j >> 5, o = j & 31;
                #pragma unroll
                for (int r = 0; r < 4; ++r)
                    sY[(rbase + r) * YNST + o * YKST + k] =
                        __bfloat16_as_ushort(__float2bfloat16(c[r]));
            } else {
                const int o = j - 2048;
                #pragma unroll
                for (int r = 0; r < 4; ++r) s_bias[rbase + r][o] = c[r];
            }
        }
    }
    __syncthreads();

    // ---- phase 2 (per-wave, no barriers, no atomics)
    const int oc = lane & 15, ks = lane >> 4;
    for (int ti = t0 + wave; ti < t1; ti += 4) {
        const unsigned T = tiles[ti];
        const int start = (int)(T >> 8);
        const int cnt   = (int)((T >> 3) & 31);
        const int row   = (int)(T & 7);
        long eidx = start + oc;
        if (eidx > NEDGES - 1) eidx = NEDGES - 1;
        const bf16x8 a0 = *reinterpret_cast<const bf16x8*>(h1s + eidx * 64 + ks * 8);
        const bf16x8 a1 = *reinterpret_cast<const bf16x8*>(h1s + eidx * 64 + 32 + ks * 8);
        int cp[4];
        #pragma unroll
        for (int r = 0; r < 4; ++r) {
            const int slot = ks * 4 + r;
            cp[r] = (slot < cnt) ? cscpos[start + slot] : -1;
        }
        #pragma unroll
        for (int ct = 0; ct < 2; ++ct) {
            const int o = ct * 16 + oc;
            const unsigned short* yp = sY + row * YNST + o * YKST;
            const bf16x8 b0 = *reinterpret_cast<const bf16x8*>(yp + ks * 8);
            const bf16x8 b1 = *reinterpret_cast<const bf16x8*>(yp + 32 + ks * 8);
            const float bias = s_bias[row][o];
            f32x4 acc = {bias, bias, bias, bias};
            acc = __builtin_amdgcn_mfma_f32_16x16x32_bf16(a0, b0, acc, 0, 0, 0);
            acc = __builtin_amdgcn_mfma_f32_16x16x32_bf16(a1, b1, acc, 0, 0, 0);
            #pragma unroll
            for (int r = 0; r < 4; ++r)
                if (cp[r] >= 0)
                    msgC[(size_t)cp[r] * NCD + o] = __float2bfloat16(acc[r]);
        }
    }
}

// ---------------------------------------------------------------------------
// GRU + CSC gather: x[n,c] = invd * sum_{e in csc[n]} msgC[e*32+c]
__global__ __launch_bounds__(256) void k_gru(
    const __hip_bfloat16* __restrict__ msgC, const int* __restrict__ csc_off,
    const float* __restrict__ indeg,
    const float* __restrict__ WiT, const float* __restrict__ WhT,
    const float* __restrict__ bi, const float* __restrict__ bh,
    float* __restrict__ out, __hip_bfloat16* __restrict__ hxb, int r) {
    __shared__ __align__(16) float sWiT[96 * 36];
    __shared__ __align__(16) float sWhT[96 * 36];
    __shared__ float s_x[8][32];
    __shared__ float s_h[8][32];
    const int t = threadIdx.x;
    const float4* WiT4 = reinterpret_cast<const float4*>(WiT);
    const float4* WhT4 = reinterpret_cast<const float4*>(WhT);
    for (int p = t; p < 768; p += 256) {
        int g = p >> 3, i = (p & 7) * 4;
        *reinterpret_cast<float4*>(&sWiT[g * 36 + i]) = WiT4[p];
        *reinterpret_cast<float4*>(&sWhT[g * 36 + i]) = WhT4[p];
    }
    const int tid = blockIdx.x * 256 + t;
    const int n   = tid >> 5;
    const int c   = t & 31;
    const int ln  = t >> 5;
    {
        const int e0 = csc_off[n], e1 = csc_off[n + 1];
        float s = 0.f;
        for (int e = e0; e < e1; ++e)
            s += __bfloat162float(msgC[(size_t)e * NCD + c]);
        const float invd = 1.0f / fmaxf(indeg[n], 1.0f);
        s_x[ln][c] = s * invd;
        s_h[ln][c] = out[(size_t)n * OUTCD + r * NCD + c];
    }
    __syncthreads();
    float ir = bi[c], iz = bi[NCD + c], in_ = bi[2 * NCD + c];
    float hr = bh[c], hz = bh[NCD + c], hn = bh[2 * NCD + c];
    const float* wi_r = &sWiT[c * 36];
    const float* wi_z = &sWiT[(NCD + c) * 36];
    const float* wi_n = &sWiT[(2 * NCD + c) * 36];
    const float* wh_r = &sWhT[c * 36];
    const float* wh_z = &sWhT[(NCD + c) * 36];
    const float* wh_n = &sWhT[(2 * NCD + c) * 36];
    #pragma unroll
    for (int i4 = 0; i4 < 8; ++i4) {
        const float4 xx = *reinterpret_cast<const float4*>(&s_x[ln][i4 * 4]);
        const float4 hh = *reinterpret_cast<const float4*>(&s_h[ln][i4 * 4]);
        const float4 a = *reinterpret_cast<const float4*>(&wi_r[i4 * 4]);
        const float4 b = *reinterpret_cast<const float4*>(&wi_z[i4 * 4]);
        const float4 g = *reinterpret_cast<const float4*>(&wi_n[i4 * 4]);
        const float4 d = *reinterpret_cast<const float4*>(&wh_r[i4 * 4]);
        const float4 e = *reinterpret_cast<const float4*>(&wh_z[i4 * 4]);
        const float4 f = *reinterpret_cast<const float4*>(&wh_n[i4 * 4]);
        ir  += xx.x * a.x + xx.y * a.y + xx.z * a.z + xx.w * a.w;
        iz  += xx.x * b.x + xx.y * b.y + xx.z * b.z + xx.w * b.w;
        in_ += xx.x * g.x + xx.y * g.y + xx.z * g.z + xx.w * g.w;
        hr  += hh.x * d.x + hh.y * d.y + hh.z * d.z + hh.w * d.w;
        hz  += hh.x * e.x + hh.y * e.y + hh.z * e.z + hh.w * e.w;
        hn  += hh.x * f.x + hh.y * f.y + hh.z * f.z + hh.w * f.w;
    }
    const float rg = 1.f / (1.f + expf(-(ir + hr)));
    const float zg = 1.f / (1.f + expf(-(iz + hz)));
    const float ng = tanhf(in_ + rg * hn);
    const float hv = (1.f - zg) * ng + zg * s_h[ln][c];
    out[(size_t)n * OUTCD + (r + 1) * NCD + c] = hv;
    hxb[(size_t)n * NCD + c] = __float2bfloat16(hv);
}

// ---------------------------------------------------------------------------
extern "C" void kernel_launch(void* const* d_in, const int* in_sizes, int n_in,
                              void* d_out, int out_size, void* d_ws, size_t ws_size,
                              hipStream_t stream) {
    const float* hx  = (const float*)d_in[0];
    const int*   ei  = (const int*)d_in[1];
    const float* ef  = (const float*)d_in[2];
    const float* fW1 = (const float*)d_in[3];
    const float* fb1 = (const float*)d_in[4];
    const float* fW2 = (const float*)d_in[5];
    const float* fb2 = (const float*)d_in[6];
    const float* Wi  = (const float*)d_in[7];
    const float* Wh  = (const float*)d_in[8];
    const float* bi  = (const float*)d_in[9];
    const float* bh  = (const float*)d_in[10];
    float* out = (float*)d_out;

    char* ws = (char*)d_ws;
    size_t off = 0;
    auto take = [&](size_t bytes) -> void* {
        void* p = ws + off;
        off = (off + bytes + 255) & ~(size_t)255;
        return p;
    };
    __hip_bfloat16* h1s  = (__hip_bfloat16*)take((size_t)NEDGES * FHIDD * 2); // 25.6 MB
    __hip_bfloat16* hxb  = (__hip_bfloat16*)take((size_t)NNODES * NCD * 2);   // 1.28 MB
    __hip_bfloat16* W2f  = (__hip_bfloat16*)take((size_t)NCT * 1024 * 2);     // 266 KB
    __hip_bfloat16* msgC = (__hip_bfloat16*)take((size_t)NEDGES * NCD * 2);   // 12.8 MB
    // contiguous zero-init region: indeg, outcnt, incnt, cursor, csc_cur
    float* indeg   = (float*)take((size_t)NNODES * 4 * 5);
    int*   outcnt  = (int*)(indeg + NNODES);
    int*   incnt   = (int*)(indeg + 2 * NNODES);
    int*   cursor  = (int*)(indeg + 3 * NNODES);
    int*   csc_cur = (int*)(indeg + 4 * NNODES);
    int*   csr_off = (int*)take((size_t)(NNODES + 1) * 4);
    int*   csc_off = (int*)take((size_t)(NNODES + 1) * 4);
    int*   rank    = (int*)take((size_t)NEDGES * 4);
    int*   cscpos  = (int*)take((size_t)NEDGES * 4);
    int*   tcnt    = (int*)take((size_t)NBLK * 4);
    int*   tile_off= (int*)take((size_t)(NBLK + 1) * 4);
    unsigned* tiles= (unsigned*)take((size_t)MAXTILES * 4);
    float* WiT     = (float*)take(3072 * 4);
    float* WhT     = (float*)take(3072 * 4);

    hipMemsetAsync(indeg, 0, (size_t)NNODES * 4 * 5, stream);
    k_copy_h0<<<(NNODES * NCD) / 256, 256, 0, stream>>>(hx, out, hxb);
    k_degrees<<<(NEDGES + 255) / 256, 256, 0, stream>>>(ei, indeg, incnt, outcnt);
    k_scan<<<1, 256, 0, stream>>>(outcnt, csr_off, NNODES);
    k_scan<<<1, 256, 0, stream>>>(incnt, csc_off, NNODES);
    k_fill<<<(NEDGES + 255) / 256, 256, 0, stream>>>(ei, csr_off, cursor, rank);
    k_cpos<<<(NEDGES + 255) / 256, 256, 0, stream>>>(ei, rank, csc_off, csc_cur, cscpos);
    k_tcnt<<<(NBLK + 255) / 256, 256, 0, stream>>>(csr_off, tcnt);
    k_scan<<<1, 256, 0, stream>>>(tcnt, tile_off, NBLK);
    k_tfill<<<(NBLK + 255) / 256, 256, 0, stream>>>(csr_off, tile_off, tiles);
    k_h1<<<NEDGES / 4, 256, 0, stream>>>(ef, fW1, fb1, rank, h1s);
    k_w2frag<<<(NCT * 64 + 255) / 256, 256, 0, stream>>>(fW2, fb2, W2f);
    k_prep<<<12, 256, 0, stream>>>(Wi, Wh, WiT, WhT);

    for (int r = 0; r < NREPD; ++r) {
        k_msg<<<NBLK, 256, 0, stream>>>(tile_off, tiles, cscpos, h1s, hxb, W2f, msgC);
        k_gru<<<(NNODES * NCD) / 256, 256, 0, stream>>>(msgC, csc_off, indeg, WiT, WhT,
                                                        bi, bh, out, hxb, r);
    }
}